// Round 1
// baseline (43291.013 us; speedup 1.0000x reference)
//
#include <hip/hip_runtime.h>
#include <stdint.h>
#include <math.h>

#define BB   8
#define TT   512
#define VV   32000
#define EE   512
#define HH   1024
#define G3H  3072

// ---- workspace layout (byte offsets) ----
#define GX0_OFF 0ULL                 // [B][T][3H] f32 = 50,331,648 B
#define H1_OFF  50331648ULL          // [2][B][H]  f32 = 65,536 B
#define H2_OFF  50397184ULL          // [B][T][H]  f32 = 16,777,216 B
#define BAR_OFF 67174400ULL          // barrier counters
#define XD_OFF  67174656ULL          // decoded indices, 4096 int32

#define NBLK2 512

// ---------------------------------------------------------------- K0: init
__global__ __launch_bounds__(1024) void k_init(const int* __restrict__ xin,
                                               int* __restrict__ xd,
                                               float* __restrict__ h1buf,
                                               unsigned* __restrict__ bar) {
    __shared__ int accum;
    const int tid = threadIdx.x;
    if (tid == 0) accum = 0;
    __syncthreads();
    // int64 detection: odd 32-bit words of first 4096 int32s are all zero iff
    // the buffer is little-endian int64 with values < 2^31.
    int v = 0;
    for (int i = tid; i < 2048; i += 1024) v |= xin[2 * i + 1];
    atomicOr(&accum, v);
    __syncthreads();
    const bool is64 = (accum == 0);
    for (int i = tid; i < BB * TT; i += 1024) xd[i] = is64 ? xin[2 * i] : xin[i];
    for (int i = tid; i < 2 * BB * HH; i += 1024) h1buf[i] = 0.f;
    if (tid < 32) bar[tid] = 0u;
}

// ------------------------------------------------- K1: embed + gx0 GEMM
// gx0[bt][g] = sum_k emb[x[bt]][k] * w_ih0[g][k] + b_ih0[g]
__global__ __launch_bounds__(256) void k_gx0(const float* __restrict__ emb,
                                             const float* __restrict__ w_ih0,
                                             const float* __restrict__ b_ih0,
                                             const int* __restrict__ xd,
                                             float* __restrict__ gx0) {
    __shared__ float As[16][68];
    __shared__ float Bs[16][68];
    const int tid = threadIdx.x;
    const int tx = tid & 15, ty = tid >> 4;
    const int n0 = blockIdx.x * 64;   // gate dim (3072)
    const int m0 = blockIdx.y * 64;   // bt dim (4096)
    const int lrow = tid >> 2;        // 0..63
    const int lk   = (tid & 3) * 4;   // 0,4,8,12
    const int arow = xd[m0 + lrow];
    const float* aptr = emb   + (size_t)arow * EE + lk;
    const float* bptr = w_ih0 + (size_t)(n0 + lrow) * EE + lk;

    float acc[4][4] = {};
    const int rbase = ty * 4, cbase = tx * 4;

    for (int k0 = 0; k0 < EE; k0 += 16) {
        const float4 a4 = *(const float4*)(aptr + k0);
        const float4 b4 = *(const float4*)(bptr + k0);
        As[lk + 0][lrow] = a4.x; As[lk + 1][lrow] = a4.y;
        As[lk + 2][lrow] = a4.z; As[lk + 3][lrow] = a4.w;
        Bs[lk + 0][lrow] = b4.x; Bs[lk + 1][lrow] = b4.y;
        Bs[lk + 2][lrow] = b4.z; Bs[lk + 3][lrow] = b4.w;
        __syncthreads();
#pragma unroll
        for (int k = 0; k < 16; ++k) {
            const float4 av = *(const float4*)&As[k][rbase];
            const float4 bv = *(const float4*)&Bs[k][cbase];
            const float a[4] = {av.x, av.y, av.z, av.w};
            const float b[4] = {bv.x, bv.y, bv.z, bv.w};
#pragma unroll
            for (int i = 0; i < 4; ++i)
#pragma unroll
                for (int j = 0; j < 4; ++j)
                    acc[i][j] = fmaf(a[i], b[j], acc[i][j]);
        }
        __syncthreads();
    }
#pragma unroll
    for (int i = 0; i < 4; ++i) {
        const int r = m0 + rbase + i;
#pragma unroll
        for (int j = 0; j < 4; ++j) {
            const int c = n0 + cbase + j;
            gx0[(size_t)r * G3H + c] = acc[i][j] + b_ih0[c];
        }
    }
}

// ------------------------------------------------- K2: persistent fused GRU
__device__ __forceinline__ float sigmf(float x) { return 1.f / (1.f + expf(-x)); }

__global__ __launch_bounds__(256, 4) void k_gru(const float* __restrict__ gx0,
                                                const float* __restrict__ w_hh0,
                                                const float* __restrict__ b_hh0,
                                                const float* __restrict__ w_ih1,
                                                const float* __restrict__ b_ih1,
                                                const float* __restrict__ w_hh1,
                                                const float* __restrict__ b_hh1,
                                                float* __restrict__ h1buf,
                                                float* __restrict__ h2seq,
                                                unsigned* __restrict__ bar) {
    const int bid = blockIdx.x;
    const int tid = threadIdx.x;
    const int wv  = tid >> 6;
    const int ln  = tid & 63;
    const int b   = ln >> 3;   // batch 0..7
    const int kk  = ln & 7;    // k-slice 0..7
    const int c0  = bid * 2;   // this block's two columns (both layers)

    __shared__ float ghbuf[18][8];

    for (int it = 0; it <= TT; ++it) {
        const float* h1p = h1buf + ((it + 1) & 1) * (BB * HH);  // h1[it-1]

        // ---- dot phase: 18 rows x 8 batches, rows striped over 4 waves
        for (int i = wv; i < 18; i += 4) {
            const int grp  = i / 6;          // 0: L0 gh, 1: L1 gx, 2: L1 gh
            const int rem  = i % 6;
            const int cl   = rem / 3;
            const int gate = rem % 3;
            const int wrow = gate * HH + c0 + cl;

            bool act;
            const float* W;
            const float* hsrc;
            if (grp == 0)      { act = (it < TT); W = w_hh0 + (size_t)wrow * HH; hsrc = h1p + b * HH; }
            else if (grp == 1) { act = (it >= 1); W = w_ih1 + (size_t)wrow * HH; hsrc = h1p + b * HH; }
            else               { act = (it >= 2); W = w_hh1 + (size_t)wrow * HH;
                                 hsrc = h2seq + ((size_t)b * TT + (it - 2)) * HH; }

            float4 acc = {0.f, 0.f, 0.f, 0.f};
            if (act) {
#pragma unroll 8
                for (int j = 0; j < 32; ++j) {
                    const int k = kk * 4 + j * 32;
                    const float4 w4 = *(const float4*)(W + k);
                    const float4 h4 = *(const float4*)(hsrc + k);
                    acc.x = fmaf(w4.x, h4.x, acc.x);
                    acc.y = fmaf(w4.y, h4.y, acc.y);
                    acc.z = fmaf(w4.z, h4.z, acc.z);
                    acc.w = fmaf(w4.w, h4.w, acc.w);
                }
            }
            float s = (acc.x + acc.y) + (acc.z + acc.w);
            s += __shfl_xor(s, 1);
            s += __shfl_xor(s, 2);
            s += __shfl_xor(s, 4);
            if (kk == 0) ghbuf[i][b] = s;
        }
        __syncthreads();

        // ---- gate phase (wave 0 only)
        if (tid < 16) {
            if (it < TT) {
                const int b2 = tid >> 1, cl = tid & 1, c = c0 + cl;
                const size_t gb = ((size_t)b2 * TT + it) * G3H;
                const float xr = gx0[gb + c];
                const float xz = gx0[gb + HH + c];
                const float xn = gx0[gb + 2 * HH + c];
                const float hr = ghbuf[cl * 3 + 0][b2] + b_hh0[c];
                const float hz = ghbuf[cl * 3 + 1][b2] + b_hh0[HH + c];
                const float hn = ghbuf[cl * 3 + 2][b2] + b_hh0[2 * HH + c];
                const float r = sigmf(xr + hr);
                const float z = sigmf(xz + hz);
                const float n = tanhf(xn + r * hn);
                const float hp = h1p[b2 * HH + c];
                h1buf[(it & 1) * (BB * HH) + b2 * HH + c] = (1.f - z) * n + z * hp;
            }
        } else if (tid < 32) {
            if (it >= 1) {
                const int t2 = tid - 16;
                const int b2 = t2 >> 1, cl = t2 & 1, c = c0 + cl;
                const int s = it - 1;
                const float xr = ghbuf[6 + cl * 3 + 0][b2] + b_ih1[c];
                const float xz = ghbuf[6 + cl * 3 + 1][b2] + b_ih1[HH + c];
                const float xn = ghbuf[6 + cl * 3 + 2][b2] + b_ih1[2 * HH + c];
                const float hr = ghbuf[12 + cl * 3 + 0][b2] + b_hh1[c];
                const float hz = ghbuf[12 + cl * 3 + 1][b2] + b_hh1[HH + c];
                const float hn = ghbuf[12 + cl * 3 + 2][b2] + b_hh1[2 * HH + c];
                const float r = sigmf(xr + hr);
                const float z = sigmf(xz + hz);
                const float n = tanhf(xn + r * hn);
                const float hp = (s >= 1) ? h2seq[((size_t)b2 * TT + (s - 1)) * HH + c] : 0.f;
                h2seq[((size_t)b2 * TT + s) * HH + c] = (1.f - z) * n + z * hp;
            }
        }

        // ---- grid barrier (monotonic counter, release/acquire)
        __syncthreads();
        if (tid == 0) {
            __threadfence();  // release: flush this XCD's L2 so writes reach L3
            __hip_atomic_fetch_add(bar, 1u, __ATOMIC_RELAXED, __HIP_MEMORY_SCOPE_AGENT);
            const unsigned target = (unsigned)NBLK2 * (unsigned)(it + 1);
            while (__hip_atomic_load(bar, __ATOMIC_RELAXED, __HIP_MEMORY_SCOPE_AGENT) < target) {
                __builtin_amdgcn_s_sleep(2);
            }
            __threadfence();  // acquire: invalidate L1/L2 before reading peers' h
        }
        __syncthreads();
    }
}

// ------------------------------------------------- K3: head GEMM
// out[bt][v] = sum_k h2[bt][k] * fc_w[v][k] + fc_b[v]
__global__ __launch_bounds__(256) void k_head(const float* __restrict__ h2,
                                              const float* __restrict__ fc_w,
                                              const float* __restrict__ fc_b,
                                              float* __restrict__ out) {
    __shared__ float As[16][136];
    __shared__ float Bs[16][136];
    const int tid = threadIdx.x;
    const int tx = tid & 15, ty = tid >> 4;
    const int m0 = blockIdx.x * 128;  // bt   (x fast-varying: consecutive blocks share n-tile)
    const int n0 = blockIdx.y * 128;  // vocab
    const int lrow = tid >> 1;        // 0..127
    const int lk   = (tid & 1) * 8;   // 0 or 8
    const float* aptr = h2   + (size_t)(m0 + lrow) * HH + lk;
    const float* bptr = fc_w + (size_t)(n0 + lrow) * HH + lk;

    float acc[8][8] = {};
    const int rbase = ty * 8, cbase = tx * 8;

    for (int k0 = 0; k0 < HH; k0 += 16) {
        const float4 a0 = *(const float4*)(aptr + k0);
        const float4 a1 = *(const float4*)(aptr + k0 + 4);
        const float4 b0 = *(const float4*)(bptr + k0);
        const float4 b1 = *(const float4*)(bptr + k0 + 4);
        As[lk + 0][lrow] = a0.x; As[lk + 1][lrow] = a0.y;
        As[lk + 2][lrow] = a0.z; As[lk + 3][lrow] = a0.w;
        As[lk + 4][lrow] = a1.x; As[lk + 5][lrow] = a1.y;
        As[lk + 6][lrow] = a1.z; As[lk + 7][lrow] = a1.w;
        Bs[lk + 0][lrow] = b0.x; Bs[lk + 1][lrow] = b0.y;
        Bs[lk + 2][lrow] = b0.z; Bs[lk + 3][lrow] = b0.w;
        Bs[lk + 4][lrow] = b1.x; Bs[lk + 5][lrow] = b1.y;
        Bs[lk + 6][lrow] = b1.z; Bs[lk + 7][lrow] = b1.w;
        __syncthreads();
#pragma unroll
        for (int k = 0; k < 16; ++k) {
            const float4 av0 = *(const float4*)&As[k][rbase];
            const float4 av1 = *(const float4*)&As[k][rbase + 4];
            const float4 bv0 = *(const float4*)&Bs[k][cbase];
            const float4 bv1 = *(const float4*)&Bs[k][cbase + 4];
            const float a[8] = {av0.x, av0.y, av0.z, av0.w, av1.x, av1.y, av1.z, av1.w};
            const float b[8] = {bv0.x, bv0.y, bv0.z, bv0.w, bv1.x, bv1.y, bv1.z, bv1.w};
#pragma unroll
            for (int i = 0; i < 8; ++i)
#pragma unroll
                for (int j = 0; j < 8; ++j)
                    acc[i][j] = fmaf(a[i], b[j], acc[i][j]);
        }
        __syncthreads();
    }
#pragma unroll
    for (int i = 0; i < 8; ++i) {
        const size_t r = (size_t)(m0 + rbase + i) * VV;
#pragma unroll
        for (int j = 0; j < 8; j += 4) {
            const int c = n0 + cbase + j;
            float4 o;
            o.x = acc[i][j + 0] + fc_b[c + 0];
            o.y = acc[i][j + 1] + fc_b[c + 1];
            o.z = acc[i][j + 2] + fc_b[c + 2];
            o.w = acc[i][j + 3] + fc_b[c + 3];
            *(float4*)(out + r + c) = o;
        }
    }
}

// ----------------------------------------------------------------- launch
extern "C" void kernel_launch(void* const* d_in, const int* in_sizes, int n_in,
                              void* d_out, int out_size, void* d_ws, size_t ws_size,
                              hipStream_t stream) {
    (void)in_sizes; (void)n_in; (void)out_size; (void)ws_size;
    const int*   xin   = (const int*)d_in[0];
    const float* emb   = (const float*)d_in[1];
    const float* w_ih0 = (const float*)d_in[2];
    const float* w_hh0 = (const float*)d_in[3];
    const float* b_ih0 = (const float*)d_in[4];
    const float* b_hh0 = (const float*)d_in[5];
    const float* w_ih1 = (const float*)d_in[6];
    const float* w_hh1 = (const float*)d_in[7];
    const float* b_ih1 = (const float*)d_in[8];
    const float* b_hh1 = (const float*)d_in[9];
    const float* fc_w  = (const float*)d_in[10];
    const float* fc_b  = (const float*)d_in[11];
    float* out = (float*)d_out;

    char* ws = (char*)d_ws;
    float*    gx0   = (float*)(ws + GX0_OFF);
    float*    h1buf = (float*)(ws + H1_OFF);
    float*    h2seq = (float*)(ws + H2_OFF);
    unsigned* bar   = (unsigned*)(ws + BAR_OFF);
    int*      xd    = (int*)(ws + XD_OFF);

    hipLaunchKernelGGL(k_init, dim3(1), dim3(1024), 0, stream, xin, xd, h1buf, bar);
    hipLaunchKernelGGL(k_gx0, dim3(48, 64), dim3(256), 0, stream,
                       emb, w_ih0, b_ih0, xd, gx0);
    hipLaunchKernelGGL(k_gru, dim3(NBLK2), dim3(256), 0, stream,
                       gx0, w_hh0, b_hh0, w_ih1, b_ih1, w_hh1, b_hh1,
                       h1buf, h2seq, bar);
    hipLaunchKernelGGL(k_head, dim3(32, 250), dim3(256), 0, stream,
                       h2seq, fc_w, fc_b, out);
}